// Round 1
// baseline (737.439 us; speedup 1.0000x reference)
//
#include <hip/hip_runtime.h>
#include <cstdint>

#define BB 32
#define HH 4096
#define FF 4096
#define EE 8
#define NSLOT 16   // 8 experts x 2 slots of <=16 tokens
#define TSEG 16

// ---------------------------------------------------------------- gate ----
__global__ __launch_bounds__(256) void gate_kernel(const float* __restrict__ x,
                                                   const float* __restrict__ Wg,
                                                   float* __restrict__ logits) {
  int b = blockIdx.x;
  int tid = threadIdx.x;
  float acc[EE];
#pragma unroll
  for (int e = 0; e < EE; ++e) acc[e] = 0.f;
  const float* xb = x + (size_t)b * HH;
  for (int h = tid; h < HH; h += 256) {
    float xv = xb[h];
    const float4* wg = (const float4*)(Wg + (size_t)h * EE);
    float4 w0 = wg[0], w1 = wg[1];
    acc[0] = fmaf(xv, w0.x, acc[0]);
    acc[1] = fmaf(xv, w0.y, acc[1]);
    acc[2] = fmaf(xv, w0.z, acc[2]);
    acc[3] = fmaf(xv, w0.w, acc[3]);
    acc[4] = fmaf(xv, w1.x, acc[4]);
    acc[5] = fmaf(xv, w1.y, acc[5]);
    acc[6] = fmaf(xv, w1.z, acc[6]);
    acc[7] = fmaf(xv, w1.w, acc[7]);
  }
#pragma unroll
  for (int off = 32; off > 0; off >>= 1) {
#pragma unroll
    for (int e = 0; e < EE; ++e) acc[e] += __shfl_down(acc[e], off, 64);
  }
  __shared__ float part[4][EE];
  if ((tid & 63) == 0) {
#pragma unroll
    for (int e = 0; e < EE; ++e) part[tid >> 6][e] = acc[e];
  }
  __syncthreads();
  if (tid < EE) {
    logits[(size_t)b * EE + tid] =
        part[0][tid] + part[1][tid] + part[2][tid] + part[3][tid];
  }
}

// --------------------------------------------------------------- route ----
__global__ void route_kernel(const float* __restrict__ logits,
                             int* __restrict__ cnt,
                             int* __restrict__ tok,
                             float* __restrict__ wts) {
  if (threadIdx.x != 0 || blockIdx.x != 0) return;
  int e0[BB], e1[BB];
  float p0[BB], p1[BB];
  for (int b = 0; b < BB; ++b) {
    const float* L = logits + (size_t)b * EE;
    int i0 = 0;
    float v0 = L[0];
    for (int e = 1; e < EE; ++e) {
      float v = L[e];
      if (v > v0) { v0 = v; i0 = e; }
    }
    int i1 = (i0 == 0) ? 1 : 0;
    float v1 = L[i1];
    for (int e = 0; e < EE; ++e) {
      if (e == i0) continue;
      float v = L[e];
      if (v > v1) { v1 = v; i1 = e; }
    }
    float p = 1.f / (1.f + __expf(v1 - v0));  // softmax over (v0 >= v1)
    e0[b] = i0; e1[b] = i1; p0[b] = p; p1[b] = 1.f - p;
  }
  for (int s = 0; s < NSLOT; ++s) {
    cnt[s] = 0;
    for (int t = 0; t < TSEG; ++t) { tok[s * TSEG + t] = 0; wts[s * TSEG + t] = 0.f; }
  }
  for (int e = 0; e < EE; ++e) {
    int c = 0;
    for (int b = 0; b < BB; ++b) {
      float w = 0.f;
      int sel = 0;
      if (e0[b] == e) { w = p0[b]; sel = 1; }
      else if (e1[b] == e) { w = p1[b]; sel = 1; }
      if (sel) {
        int s = e * 2 + (c >> 4);
        int t = c & 15;
        tok[s * TSEG + t] = b;
        wts[s * TSEG + t] = w;
        cnt[s] = t + 1;
        ++c;
      }
    }
  }
}

// -------------------------------------------------------------- buildx ----
// xseg[slot][h][16] = x[tok][h], zero-padded beyond cnt. Written fully every
// call (deterministic, no stale ws state).
__global__ __launch_bounds__(256) void buildx_kernel(const float* __restrict__ x,
                                                     const int* __restrict__ cnt,
                                                     const int* __restrict__ tok,
                                                     float* __restrict__ xseg) {
  int s = blockIdx.y;
  int tid = threadIdx.x;
  int t = tid & 15;
  int hoff = tid >> 4;
  int c = cnt[s];
  int tk = tok[s * TSEG + t];
  bool act = t < c;
  int hbase = blockIdx.x * 256;
#pragma unroll
  for (int i = 0; i < 16; ++i) {
    int h = hbase + i * 16 + hoff;
    float v = act ? x[(size_t)tk * HH + h] : 0.f;
    xseg[((size_t)s * HH + h) * TSEG + t] = v;
  }
}

// --------------------------------------------------------------- passB ----
// g = silu(x @ W1[e]) * (x @ W3[e])  for the <=16 tokens of one slot.
// Block: 64 f-columns x 4 h-slices of 1024. Wave-coalesced W loads,
// wave-uniform xseg loads, 16 fp32 accumulators per matrix per thread.
__global__ __launch_bounds__(256) void passB_kernel(const float* __restrict__ W1,
                                                    const float* __restrict__ W3,
                                                    const float* __restrict__ xseg,
                                                    float* __restrict__ gseg,
                                                    const int* __restrict__ cnt) {
  int s = blockIdx.y;
  int c = cnt[s];
  if (c == 0) return;
  int e = s >> 1;
  int tid = threadIdx.x;
  int fl = tid & 63;
  int slice = tid >> 6;
  int f = blockIdx.x * 64 + fl;
  int h0 = __builtin_amdgcn_readfirstlane(slice << 10);
  const float* w1p = W1 + (size_t)e * HH * FF + (size_t)h0 * FF + f;
  const float* w3p = W3 + (size_t)e * HH * FF + (size_t)h0 * FF + f;
  const float* xp = xseg + ((size_t)s * HH + h0) * TSEG;
  float a1[TSEG], a3[TSEG];
#pragma unroll
  for (int t = 0; t < TSEG; ++t) { a1[t] = 0.f; a3[t] = 0.f; }
#pragma unroll 2
  for (int i = 0; i < 1024; ++i) {
    float w1v = w1p[(size_t)i * FF];
    float w3v = w3p[(size_t)i * FF];
    float xs[TSEG];
    *(float4*)&xs[0]  = *(const float4*)(xp + (size_t)i * TSEG + 0);
    *(float4*)&xs[4]  = *(const float4*)(xp + (size_t)i * TSEG + 4);
    *(float4*)&xs[8]  = *(const float4*)(xp + (size_t)i * TSEG + 8);
    *(float4*)&xs[12] = *(const float4*)(xp + (size_t)i * TSEG + 12);
#pragma unroll
    for (int t = 0; t < TSEG; ++t) {
      a1[t] = fmaf(xs[t], w1v, a1[t]);
      a3[t] = fmaf(xs[t], w3v, a3[t]);
    }
  }
  __shared__ float red[4][64][TSEG + 1];
#pragma unroll
  for (int t = 0; t < TSEG; ++t) red[slice][fl][t] = a1[t];
  __syncthreads();
  int tg = tid >> 6;
  float h1v[4];
#pragma unroll
  for (int j = 0; j < 4; ++j) {
    int t = tg * 4 + j;
    h1v[j] = red[0][fl][t] + red[1][fl][t] + red[2][fl][t] + red[3][fl][t];
  }
  __syncthreads();
#pragma unroll
  for (int t = 0; t < TSEG; ++t) red[slice][fl][t] = a3[t];
  __syncthreads();
  float* gout = gseg + ((size_t)s * FF + (size_t)blockIdx.x * 64 + fl) * TSEG;
#pragma unroll
  for (int j = 0; j < 4; ++j) {
    int t = tg * 4 + j;
    float h3 = red[0][fl][t] + red[1][fl][t] + red[2][fl][t] + red[3][fl][t];
    float h1 = h1v[j];
    float sig = 1.f / (1.f + __expf(-h1));
    gout[t] = (h1 * sig) * h3;
  }
}

// --------------------------------------------------------------- passC ----
// y = g @ W2[e]; out[tok] += gate_weight * y (atomic; exactly 2 adds/element)
__global__ __launch_bounds__(256) void passC_kernel(const float* __restrict__ W2,
                                                    const float* __restrict__ gseg,
                                                    const int* __restrict__ cnt,
                                                    const int* __restrict__ tok,
                                                    const float* __restrict__ wts,
                                                    float* __restrict__ out) {
  int s = blockIdx.y;
  int c = cnt[s];
  if (c == 0) return;
  int e = s >> 1;
  int tid = threadIdx.x;
  int hl = tid & 63;
  int slice = tid >> 6;
  int hh = blockIdx.x * 64 + hl;
  int f0 = __builtin_amdgcn_readfirstlane(slice << 10);
  const float* w2p = W2 + (size_t)e * FF * HH + (size_t)f0 * HH + hh;
  const float* gp = gseg + ((size_t)s * FF + f0) * TSEG;
  float acc[TSEG];
#pragma unroll
  for (int t = 0; t < TSEG; ++t) acc[t] = 0.f;
#pragma unroll 2
  for (int i = 0; i < 1024; ++i) {
    float w2v = w2p[(size_t)i * HH];
    float gs[TSEG];
    *(float4*)&gs[0]  = *(const float4*)(gp + (size_t)i * TSEG + 0);
    *(float4*)&gs[4]  = *(const float4*)(gp + (size_t)i * TSEG + 4);
    *(float4*)&gs[8]  = *(const float4*)(gp + (size_t)i * TSEG + 8);
    *(float4*)&gs[12] = *(const float4*)(gp + (size_t)i * TSEG + 12);
#pragma unroll
    for (int t = 0; t < TSEG; ++t) acc[t] = fmaf(gs[t], w2v, acc[t]);
  }
  __shared__ float red[4][64][TSEG + 1];
#pragma unroll
  for (int t = 0; t < TSEG; ++t) red[slice][hl][t] = acc[t];
  __syncthreads();
  int tg = tid >> 6;
#pragma unroll
  for (int j = 0; j < 4; ++j) {
    int t = tg * 4 + j;
    if (t < c) {
      float y = red[0][hl][t] + red[1][hl][t] + red[2][hl][t] + red[3][hl][t];
      atomicAdd(out + (size_t)tok[s * TSEG + t] * HH + hh, wts[s * TSEG + t] * y);
    }
  }
}

// -------------------------------------------------------------- launch ----
extern "C" void kernel_launch(void* const* d_in, const int* in_sizes, int n_in,
                              void* d_out, int out_size, void* d_ws, size_t ws_size,
                              hipStream_t stream) {
  const float* x  = (const float*)d_in[0];
  const float* Wg = (const float*)d_in[1];
  const float* W1 = (const float*)d_in[2];
  const float* W3 = (const float*)d_in[3];
  const float* W2 = (const float*)d_in[4];
  float* out = (float*)d_out;

  char* ws = (char*)d_ws;
  float* logits = (float*)ws;                 // 256 f32
  int*   cnt    = (int*)(ws + 1024);          // 16 i32
  int*   tok    = (int*)(ws + 1088);          // 256 i32
  float* wts    = (float*)(ws + 2112);        // 256 f32
  float* xseg   = (float*)(ws + 4096);        // 16*4096*16 f32 = 4 MB
  float* gseg   = xseg + (size_t)NSLOT * HH * TSEG;  // 4 MB

  hipMemsetAsync(d_out, 0, (size_t)out_size * sizeof(float), stream);
  gate_kernel<<<BB, 256, 0, stream>>>(x, Wg, logits);
  route_kernel<<<1, 64, 0, stream>>>(logits, cnt, tok, wts);
  buildx_kernel<<<dim3(HH / 256, NSLOT), 256, 0, stream>>>(x, cnt, tok, xseg);
  passB_kernel<<<dim3(FF / 64, NSLOT), 256, 0, stream>>>(W1, W3, xseg, gseg, cnt);
  passC_kernel<<<dim3(HH / 64, NSLOT), 256, 0, stream>>>(W2, gseg, cnt, tok, wts, out);
}

// Round 2
// 642.119 us; speedup vs baseline: 1.1484x; 1.1484x over previous
//
#include <hip/hip_runtime.h>
#include <cstdint>

#define BB 32
#define HH 4096
#define FF 4096
#define EE 8
#define NSLOT 16   // 8 experts x 2 slots of <=16 tokens
#define TSEG 16
#define NCH 4      // reduction-dim chunks (h in passB, f in passC)
#define CHROWS (HH / NCH)      // 1024 rows per chunk
#define WROWS (CHROWS / 4)     // 256 rows per wave

// ---------------------------------------------------------------- gate ----
__global__ __launch_bounds__(256) void gate_kernel(const float* __restrict__ x,
                                                   const float* __restrict__ Wg,
                                                   float* __restrict__ logits) {
  int b = blockIdx.x;
  int tid = threadIdx.x;
  float acc[EE];
#pragma unroll
  for (int e = 0; e < EE; ++e) acc[e] = 0.f;
  const float* xb = x + (size_t)b * HH;
  for (int h = tid; h < HH; h += 256) {
    float xv = xb[h];
    const float4* wg = (const float4*)(Wg + (size_t)h * EE);
    float4 w0 = wg[0], w1 = wg[1];
    acc[0] = fmaf(xv, w0.x, acc[0]);
    acc[1] = fmaf(xv, w0.y, acc[1]);
    acc[2] = fmaf(xv, w0.z, acc[2]);
    acc[3] = fmaf(xv, w0.w, acc[3]);
    acc[4] = fmaf(xv, w1.x, acc[4]);
    acc[5] = fmaf(xv, w1.y, acc[5]);
    acc[6] = fmaf(xv, w1.z, acc[6]);
    acc[7] = fmaf(xv, w1.w, acc[7]);
  }
#pragma unroll
  for (int off = 32; off > 0; off >>= 1) {
#pragma unroll
    for (int e = 0; e < EE; ++e) acc[e] += __shfl_down(acc[e], off, 64);
  }
  __shared__ float part[4][EE];
  if ((tid & 63) == 0) {
#pragma unroll
    for (int e = 0; e < EE; ++e) part[tid >> 6][e] = acc[e];
  }
  __syncthreads();
  if (tid < EE) {
    logits[(size_t)b * EE + tid] =
        part[0][tid] + part[1][tid] + part[2][tid] + part[3][tid];
  }
}

// --------------------------------------------------------------- route ----
__global__ void route_kernel(const float* __restrict__ logits,
                             int* __restrict__ cnt,
                             int* __restrict__ tok,
                             float* __restrict__ wts) {
  if (threadIdx.x != 0 || blockIdx.x != 0) return;
  int e0[BB], e1[BB];
  float p0[BB], p1[BB];
  for (int b = 0; b < BB; ++b) {
    const float* L = logits + (size_t)b * EE;
    int i0 = 0;
    float v0 = L[0];
    for (int e = 1; e < EE; ++e) {
      float v = L[e];
      if (v > v0) { v0 = v; i0 = e; }
    }
    int i1 = (i0 == 0) ? 1 : 0;
    float v1 = L[i1];
    for (int e = 0; e < EE; ++e) {
      if (e == i0) continue;
      float v = L[e];
      if (v > v1) { v1 = v; i1 = e; }
    }
    float p = 1.f / (1.f + __expf(v1 - v0));
    e0[b] = i0; e1[b] = i1; p0[b] = p; p1[b] = 1.f - p;
  }
  for (int s = 0; s < NSLOT; ++s) {
    cnt[s] = 0;
    for (int t = 0; t < TSEG; ++t) { tok[s * TSEG + t] = 0; wts[s * TSEG + t] = 0.f; }
  }
  for (int e = 0; e < EE; ++e) {
    int c = 0;
    for (int b = 0; b < BB; ++b) {
      float w = 0.f;
      int sel = 0;
      if (e0[b] == e) { w = p0[b]; sel = 1; }
      else if (e1[b] == e) { w = p1[b]; sel = 1; }
      if (sel) {
        int s = e * 2 + (c >> 4);
        int t = c & 15;
        tok[s * TSEG + t] = b;
        wts[s * TSEG + t] = w;
        cnt[s] = t + 1;
        ++c;
      }
    }
  }
}

// -------------------------------------------------------------- buildx ----
__global__ __launch_bounds__(256) void buildx_kernel(const float* __restrict__ x,
                                                     const int* __restrict__ cnt,
                                                     const int* __restrict__ tok,
                                                     float* __restrict__ xseg) {
  int s = blockIdx.y;
  int tid = threadIdx.x;
  int t = tid & 15;
  int hoff = tid >> 4;
  int c = cnt[s];
  int tk = tok[s * TSEG + t];
  bool act = t < c;
  int hbase = blockIdx.x * 256;
#pragma unroll
  for (int i = 0; i < 16; ++i) {
    int h = hbase + i * 16 + hoff;
    float v = act ? x[(size_t)tk * HH + h] : 0.f;
    xseg[((size_t)s * HH + h) * TSEG + t] = v;
  }
}

// --------------------------------------------------------------- passB ----
// Partial h1 = x@W1, h3 = x@W3 over one h-chunk; atomicAdd into h1seg/h3seg.
// Block: 128 f-cols (float2/lane) x 4 waves x 256 rows each.
__global__ __launch_bounds__(256, 4) void passB2_kernel(const float* __restrict__ W1,
                                                        const float* __restrict__ W3,
                                                        const float* __restrict__ xseg,
                                                        float* __restrict__ h1seg,
                                                        float* __restrict__ h3seg,
                                                        const int* __restrict__ cnt) {
  int s = blockIdx.y;
  if (cnt[s] == 0) return;
  int e = s >> 1;
  int tid = threadIdx.x;
  int l = tid & 63;
  int w = tid >> 6;
  int fbase = blockIdx.x * 128;
  int col = fbase + 2 * l;
  int h0 = blockIdx.z * CHROWS + w * WROWS;
  const float* w1p = W1 + (size_t)e * HH * FF + (size_t)h0 * FF + col;
  const float* w3p = W3 + (size_t)e * HH * FF + (size_t)h0 * FF + col;
  const float* xp = xseg + ((size_t)s * HH + h0) * TSEG;
  float2 a1[TSEG], a3[TSEG];
#pragma unroll
  for (int t = 0; t < TSEG; ++t) {
    a1[t] = make_float2(0.f, 0.f);
    a3[t] = make_float2(0.f, 0.f);
  }
#pragma unroll 2
  for (int i = 0; i < WROWS; ++i) {
    float2 w1v = *(const float2*)(w1p + (size_t)i * FF);
    float2 w3v = *(const float2*)(w3p + (size_t)i * FF);
    float xs[TSEG];
    *(float4*)&xs[0]  = *(const float4*)(xp + (size_t)i * TSEG + 0);
    *(float4*)&xs[4]  = *(const float4*)(xp + (size_t)i * TSEG + 4);
    *(float4*)&xs[8]  = *(const float4*)(xp + (size_t)i * TSEG + 8);
    *(float4*)&xs[12] = *(const float4*)(xp + (size_t)i * TSEG + 12);
#pragma unroll
    for (int t = 0; t < TSEG; ++t) {
      a1[t].x = fmaf(xs[t], w1v.x, a1[t].x);
      a1[t].y = fmaf(xs[t], w1v.y, a1[t].y);
      a3[t].x = fmaf(xs[t], w3v.x, a3[t].x);
      a3[t].y = fmaf(xs[t], w3v.y, a3[t].y);
    }
  }
  __shared__ float red[4][128][TSEG + 1];
#pragma unroll
  for (int t = 0; t < TSEG; ++t) {
    red[w][2 * l][t] = a1[t].x;
    red[w][2 * l + 1][t] = a1[t].y;
  }
  __syncthreads();
  float* h1out = h1seg + ((size_t)s * FF + fbase) * TSEG;
#pragma unroll
  for (int k = 0; k < 8; ++k) {
    int flat = tid * 8 + k;
    int cc = flat >> 4;
    int t = flat & 15;
    float v = red[0][cc][t] + red[1][cc][t] + red[2][cc][t] + red[3][cc][t];
    atomicAdd(h1out + (size_t)cc * TSEG + t, v);
  }
  __syncthreads();
#pragma unroll
  for (int t = 0; t < TSEG; ++t) {
    red[w][2 * l][t] = a3[t].x;
    red[w][2 * l + 1][t] = a3[t].y;
  }
  __syncthreads();
  float* h3out = h3seg + ((size_t)s * FF + fbase) * TSEG;
#pragma unroll
  for (int k = 0; k < 8; ++k) {
    int flat = tid * 8 + k;
    int cc = flat >> 4;
    int t = flat & 15;
    float v = red[0][cc][t] + red[1][cc][t] + red[2][cc][t] + red[3][cc][t];
    atomicAdd(h3out + (size_t)cc * TSEG + t, v);
  }
}

// ------------------------------------------------------------- combine ----
// gseg (in-place over h1seg) = silu(h1) * h3
__global__ __launch_bounds__(256) void silu_combine_kernel(float* __restrict__ h1seg,
                                                           const float* __restrict__ h3seg) {
  size_t i = (size_t)blockIdx.x * 256 + threadIdx.x;  // float4 index
  float4 h1 = ((const float4*)h1seg)[i];
  float4 h3 = ((const float4*)h3seg)[i];
  float4 r;
  r.x = (h1.x / (1.f + __expf(-h1.x))) * h3.x;
  r.y = (h1.y / (1.f + __expf(-h1.y))) * h3.y;
  r.z = (h1.z / (1.f + __expf(-h1.z))) * h3.z;
  r.w = (h1.w / (1.f + __expf(-h1.w))) * h3.w;
  ((float4*)h1seg)[i] = r;
}

// --------------------------------------------------------------- passC ----
// y = g @ W2[e] over one f-chunk; atomicAdd wt*y into out.
__global__ __launch_bounds__(256, 4) void passC2_kernel(const float* __restrict__ W2,
                                                        const float* __restrict__ gseg,
                                                        const int* __restrict__ cnt,
                                                        const int* __restrict__ tok,
                                                        const float* __restrict__ wts,
                                                        float* __restrict__ out) {
  int s = blockIdx.y;
  int c = cnt[s];
  if (c == 0) return;
  int e = s >> 1;
  int tid = threadIdx.x;
  int l = tid & 63;
  int w = tid >> 6;
  int hbase = blockIdx.x * 128;
  int hcol = hbase + 2 * l;
  int f0 = blockIdx.z * CHROWS + w * WROWS;
  const float* w2p = W2 + (size_t)e * FF * HH + (size_t)f0 * HH + hcol;
  const float* gp = gseg + ((size_t)s * FF + f0) * TSEG;
  float2 acc[TSEG];
#pragma unroll
  for (int t = 0; t < TSEG; ++t) acc[t] = make_float2(0.f, 0.f);
#pragma unroll 2
  for (int i = 0; i < WROWS; ++i) {
    float2 wv = *(const float2*)(w2p + (size_t)i * HH);
    float gs[TSEG];
    *(float4*)&gs[0]  = *(const float4*)(gp + (size_t)i * TSEG + 0);
    *(float4*)&gs[4]  = *(const float4*)(gp + (size_t)i * TSEG + 4);
    *(float4*)&gs[8]  = *(const float4*)(gp + (size_t)i * TSEG + 8);
    *(float4*)&gs[12] = *(const float4*)(gp + (size_t)i * TSEG + 12);
#pragma unroll
    for (int t = 0; t < TSEG; ++t) {
      acc[t].x = fmaf(gs[t], wv.x, acc[t].x);
      acc[t].y = fmaf(gs[t], wv.y, acc[t].y);
    }
  }
  __shared__ float red[4][128][TSEG + 1];
  __shared__ int stok[TSEG];
  __shared__ float swt[TSEG];
  if (tid < TSEG) {
    stok[tid] = tok[s * TSEG + tid];
    swt[tid] = wts[s * TSEG + tid];
  }
#pragma unroll
  for (int t = 0; t < TSEG; ++t) {
    red[w][2 * l][t] = acc[t].x;
    red[w][2 * l + 1][t] = acc[t].y;
  }
  __syncthreads();
#pragma unroll
  for (int k = 0; k < 8; ++k) {
    int flat = tid * 8 + k;
    int cc = flat >> 4;
    int t = flat & 15;
    if (t < c) {
      float y = red[0][cc][t] + red[1][cc][t] + red[2][cc][t] + red[3][cc][t];
      atomicAdd(out + (size_t)stok[t] * HH + hbase + cc, swt[t] * y);
    }
  }
}

// -------------------------------------------------------------- launch ----
extern "C" void kernel_launch(void* const* d_in, const int* in_sizes, int n_in,
                              void* d_out, int out_size, void* d_ws, size_t ws_size,
                              hipStream_t stream) {
  const float* x  = (const float*)d_in[0];
  const float* Wg = (const float*)d_in[1];
  const float* W1 = (const float*)d_in[2];
  const float* W3 = (const float*)d_in[3];
  const float* W2 = (const float*)d_in[4];
  float* out = (float*)d_out;

  char* ws = (char*)d_ws;
  float* logits = (float*)ws;                 // 256 f32
  int*   cnt    = (int*)(ws + 1024);          // 16 i32
  int*   tok    = (int*)(ws + 1088);          // 256 i32
  float* wts    = (float*)(ws + 2112);        // 256 f32
  float* xseg   = (float*)(ws + 4096);                 // 4 MB
  float* h1seg  = xseg + (size_t)NSLOT * HH * TSEG;    // 4 MB
  float* h3seg  = h1seg + (size_t)NSLOT * FF * TSEG;   // 4 MB

  hipMemsetAsync(d_out, 0, (size_t)out_size * sizeof(float), stream);
  hipMemsetAsync(h1seg, 0, (size_t)2 * NSLOT * FF * TSEG * sizeof(float), stream);
  gate_kernel<<<BB, 256, 0, stream>>>(x, Wg, logits);
  route_kernel<<<1, 64, 0, stream>>>(logits, cnt, tok, wts);
  buildx_kernel<<<dim3(HH / 256, NSLOT), 256, 0, stream>>>(x, cnt, tok, xseg);
  passB2_kernel<<<dim3(FF / 128, NSLOT, NCH), 256, 0, stream>>>(W1, W3, xseg, h1seg, h3seg, cnt);
  silu_combine_kernel<<<(NSLOT * FF * TSEG) / (256 * 4), 256, 0, stream>>>(h1seg, h3seg);
  passC2_kernel<<<dim3(HH / 128, NSLOT, NCH), 256, 0, stream>>>(W2, h1seg, cnt, tok, wts, out);
}